// Round 1
// baseline (45.249 us; speedup 1.0000x reference)
//
#include <hip/hip_runtime.h>

#define Bb 256
#define Nn 64
#define Dd 128
#define Hh 64
#define NW 8            // waves per block
#define RPW (Nn / NW)   // rows per wave = 8

__global__ __launch_bounds__(512, 1) void gcm_kernel(
    const float* __restrict__ obs,      // B*N*D
    const float* __restrict__ enc_w,    // D*H
    const float* __restrict__ enc_b,    // H
    const float* __restrict__ gate_w1,  // 2H*H
    const float* __restrict__ gate_b1,  // H
    const float* __restrict__ gate_w2,  // H (x1)
    const float* __restrict__ gate_b2,  // 1
    const float* __restrict__ msg_w1,   // H*H
    const float* __restrict__ msg_b1,   // H
    const float* __restrict__ msg_w2,   // H*H
    const float* __restrict__ msg_b2,   // H
    float* __restrict__ out)            // B*N*H
{
    const int b    = blockIdx.x;
    const int t    = threadIdx.x;
    const int lane = t & 63;
    const int wv   = t >> 6;            // 0..7
    const int row0 = wv * RPW;          // first row this wave owns

    __shared__ float s_enc[Nn][Hh];     // 16 KB  (reads are broadcast -> no pad)
    __shared__ float s_gi [Nn][Hh];     // 16 KB  (broadcast reads)
    __shared__ float s_gj [Nn][Hh + 1]; // padded: lane-varying row reads in gates phase
    __shared__ float s_msg[Nn][Hh + 1]; // padded
    __shared__ float s_tmp[Nn][Hh + 1]; // msgh, then gates
    __shared__ float s_w2 [Hh];

    if (t < Hh) s_w2[t] = gate_w2[t];

    // ---------- enc = relu(obs @ enc_w + enc_b) ----------
    {
        float acc[RPW];
        const float be = enc_b[lane];
        #pragma unroll
        for (int r = 0; r < RPW; ++r) acc[r] = be;
        const float* ob = obs + ((size_t)b * Nn + row0) * Dd;
        for (int d = 0; d < Dd; ++d) {
            const float w = enc_w[d * Hh + lane];           // coalesced, L2-hot
            #pragma unroll
            for (int r = 0; r < RPW; ++r)
                acc[r] = fmaf(ob[r * Dd + d], w, acc[r]);   // broadcast loads
        }
        #pragma unroll
        for (int r = 0; r < RPW; ++r)
            s_enc[row0 + r][lane] = fmaxf(acc[r], 0.f);
    }
    __syncthreads();

    // ---------- gi = enc@w_i ; gj = enc@w_j + b1 ; msgh = relu(enc@msg_w1 + msg_b1) ----------
    {
        float agi[RPW], agj[RPW], amh[RPW];
        const float b1 = gate_b1[lane];
        const float bm = msg_b1[lane];
        #pragma unroll
        for (int r = 0; r < RPW; ++r) { agi[r] = 0.f; agj[r] = b1; amh[r] = bm; }
        for (int k = 0; k < Hh; ++k) {
            const float wi = gate_w1[k * Hh + lane];
            const float wj = gate_w1[(Hh + k) * Hh + lane];
            const float wm = msg_w1[k * Hh + lane];
            #pragma unroll
            for (int r = 0; r < RPW; ++r) {
                const float e = s_enc[row0 + r][k];          // LDS broadcast
                agi[r] = fmaf(e, wi, agi[r]);
                agj[r] = fmaf(e, wj, agj[r]);
                amh[r] = fmaf(e, wm, amh[r]);
            }
        }
        #pragma unroll
        for (int r = 0; r < RPW; ++r) {
            s_gi [row0 + r][lane] = agi[r];
            s_gj [row0 + r][lane] = agj[r];
            s_tmp[row0 + r][lane] = fmaxf(amh[r], 0.f);      // msgh
        }
    }
    __syncthreads();

    // ---------- msg = msgh @ msg_w2 + msg_b2 ----------
    {
        float am[RPW];
        const float bm2 = msg_b2[lane];
        #pragma unroll
        for (int r = 0; r < RPW; ++r) am[r] = bm2;
        for (int k = 0; k < Hh; ++k) {
            const float wm2 = msg_w2[k * Hh + lane];
            #pragma unroll
            for (int r = 0; r < RPW; ++r)
                am[r] = fmaf(s_tmp[row0 + r][k], wm2, am[r]); // own-wave rows only
        }
        #pragma unroll
        for (int r = 0; r < RPW; ++r)
            s_msg[row0 + r][lane] = am[r];
    }
    __syncthreads();

    // ---------- gates[i][j] = sigmoid( relu(gi[i]+gj[j]) . w2 + b2 ) ----------
    {
        float ag[RPW];
        const float b2 = gate_b2[0];
        #pragma unroll
        for (int r = 0; r < RPW; ++r) ag[r] = 0.f;
        for (int h = 0; h < Hh; ++h) {
            const float gjv = s_gj[lane][h];                 // lane = j; pad -> 2-way (free)
            const float w2v = s_w2[h];                       // broadcast
            #pragma unroll
            for (int r = 0; r < RPW; ++r) {
                const float hid = s_gi[row0 + r][h] + gjv;   // broadcast
                ag[r] = fmaf(fmaxf(hid, 0.f), w2v, ag[r]);
            }
        }
        #pragma unroll
        for (int r = 0; r < RPW; ++r) {
            const float x = ag[r] + b2;
            const float g = 1.f / (1.f + __expf(-x));
            s_tmp[row0 + r][lane] = g;                       // gates row i, col j=lane
        }
    }
    __syncthreads();

    // ---------- enhanced = gates @ msg ----------
    {
        float ae[RPW];
        #pragma unroll
        for (int r = 0; r < RPW; ++r) ae[r] = 0.f;
        for (int j = 0; j < Nn; ++j) {
            const float m = s_msg[j][lane];                  // 2-way aliasing (free)
            #pragma unroll
            for (int r = 0; r < RPW; ++r)
                ae[r] = fmaf(s_tmp[row0 + r][j], m, ae[r]);  // broadcast
        }
        #pragma unroll
        for (int r = 0; r < RPW; ++r)
            out[((size_t)b * Nn + row0 + r) * Hh + lane] = ae[r];
    }
}

extern "C" void kernel_launch(void* const* d_in, const int* in_sizes, int n_in,
                              void* d_out, int out_size, void* d_ws, size_t ws_size,
                              hipStream_t stream) {
    const float* obs     = (const float*)d_in[0];
    const float* enc_w   = (const float*)d_in[1];
    const float* enc_b   = (const float*)d_in[2];
    const float* gate_w1 = (const float*)d_in[3];
    const float* gate_b1 = (const float*)d_in[4];
    const float* gate_w2 = (const float*)d_in[5];
    const float* gate_b2 = (const float*)d_in[6];
    const float* msg_w1  = (const float*)d_in[7];
    const float* msg_b1  = (const float*)d_in[8];
    const float* msg_w2  = (const float*)d_in[9];
    const float* msg_b2  = (const float*)d_in[10];
    float* out = (float*)d_out;

    gcm_kernel<<<Bb, 512, 0, stream>>>(obs, enc_w, enc_b, gate_w1, gate_b1,
                                       gate_w2, gate_b2, msg_w1, msg_b1,
                                       msg_w2, msg_b2, out);
}

// Round 2
// 29.405 us; speedup vs baseline: 1.5388x; 1.5388x over previous
//
#include <hip/hip_runtime.h>

typedef float  f32x4  __attribute__((ext_vector_type(4)));
typedef short  bf16x8 __attribute__((ext_vector_type(8)));

#define Bb 256
#define Nn 64
#define Dd 128
#define Hh 64

__device__ __forceinline__ ushort f2b(float f) {
    uint x = __float_as_uint(f);
    uint r = (x + 0x7FFFu + ((x >> 16) & 1u)) >> 16;   // RNE
    return (ushort)r;
}

__global__ __launch_bounds__(512, 1) void gcm_kernel(
    const float* __restrict__ obs,      // B*N*D
    const float* __restrict__ enc_w,    // D*H
    const float* __restrict__ enc_b,    // H
    const float* __restrict__ gate_w1,  // 2H*H
    const float* __restrict__ gate_b1,  // H
    const float* __restrict__ gate_w2,  // H
    const float* __restrict__ gate_b2,  // 1
    const float* __restrict__ msg_w1,   // H*H
    const float* __restrict__ msg_b1,   // H
    const float* __restrict__ msg_w2,   // H*H
    const float* __restrict__ msg_b2,   // H
    float* __restrict__ out)            // B*N*H
{
    const int bb   = blockIdx.x;
    const int t    = threadIdx.x;
    const int lane = t & 63;
    const int wv   = t >> 6;            // 0..7
    const int lr   = lane & 15;         // row/col within 16-tile
    const int lg   = lane >> 4;         // k-group 0..3

    // bf16 operand stores, XOR-swizzled in 16B granules: elem ^= (row&7)<<3
    __shared__ __align__(16) ushort s_encwT[Hh * Dd];   // [n<64][k<128]
    __shared__ __align__(16) ushort s_wT[256 * Hh];     // [n<256][k<64]: wi|wj|msgw1|msgw2 (transposed)
    __shared__ __align__(16) ushort s_enc [Nn * Hh];    // [row][h]
    __shared__ __align__(16) ushort s_msgh[Nn * Hh];    // [row][h]
    __shared__ __align__(16) float  s_gi   [Nn][68];
    __shared__ __align__(16) float  s_gj   [Nn][68];
    __shared__ __align__(16) float  s_gates[Nn][68];
    __shared__             float  s_msg  [Nn][65];
    __shared__ __align__(16) float  s_w2[Hh];

    if (t < Hh) s_w2[t] = gate_w2[t];

    // ---- stage enc_w^T (bf16, swizzled): encwT[n][k] = enc_w[k*H + n]
    for (int idx = t; idx < Hh * Dd; idx += 512) {
        int n = idx >> 7, k = idx & 127;
        float v = enc_w[k * Hh + n];
        s_encwT[(n * Dd + k) ^ ((n & 7) << 3)] = f2b(v);
    }
    // ---- stage wT rows: [0,64)=w_i  [64,128)=w_j  [128,192)=msg_w1  [192,256)=msg_w2
    for (int idx = t; idx < 256 * Hh; idx += 512) {
        int n = idx >> 6, k = idx & 63;
        float v;
        if (n < 64)       v = gate_w1[k * Hh + n];
        else if (n < 128) v = gate_w1[(Hh + k) * Hh + (n - 64)];
        else if (n < 192) v = msg_w1[k * Hh + (n - 128)];
        else              v = msg_w2[k * Hh + (n - 192)];
        s_wT[(n * Hh + k) ^ ((n & 7) << 3)] = f2b(v);
    }
    __syncthreads();

    const int r0 = (wv >> 1) * 16;      // wave's 16-row block (phases 1-3)

    // ---------- phase 1: enc = relu(obs @ enc_w + enc_b), M=64 K=128 N=64 ----------
    {
        const int c0 = (wv & 1) * 32;
        f32x4 acc[2];
        #pragma unroll
        for (int j = 0; j < 2; ++j) acc[j] = (f32x4){0.f, 0.f, 0.f, 0.f};
        #pragma unroll
        for (int ks = 0; ks < 4; ++ks) {
            const int d0 = ks * 32 + lg * 8;
            const float* src = obs + ((size_t)bb * Nn + r0 + lr) * Dd + d0;
            float4 f0 = *(const float4*)src;
            float4 f1 = *(const float4*)(src + 4);
            bf16x8 a;
            a[0] = (short)f2b(f0.x); a[1] = (short)f2b(f0.y);
            a[2] = (short)f2b(f0.z); a[3] = (short)f2b(f0.w);
            a[4] = (short)f2b(f1.x); a[5] = (short)f2b(f1.y);
            a[6] = (short)f2b(f1.z); a[7] = (short)f2b(f1.w);
            #pragma unroll
            for (int j = 0; j < 2; ++j) {
                const int n = c0 + j * 16 + lr;
                bf16x8 bf = *(const bf16x8*)(s_encwT + ((n * Dd + d0) ^ ((n & 7) << 3)));
                acc[j] = __builtin_amdgcn_mfma_f32_16x16x32_bf16(a, bf, acc[j], 0, 0, 0);
            }
        }
        #pragma unroll
        for (int j = 0; j < 2; ++j) {
            const int cc = c0 + j * 16 + lr;
            const float bias = enc_b[cc];
            #pragma unroll
            for (int rr = 0; rr < 4; ++rr) {
                const int row = r0 + lg * 4 + rr;
                float v = fmaxf(acc[j][rr] + bias, 0.f);
                s_enc[(row * Hh + cc) ^ ((row & 7) << 3)] = f2b(v);
            }
        }
    }
    __syncthreads();

    // ---------- phase 2: [gi | gj | msgh] = enc @ [w_i | w_j | msg_w1], N=192 K=64 ----------
    {
        const int nb = (wv & 1) * 96;
        f32x4 acc[6];
        #pragma unroll
        for (int j = 0; j < 6; ++j) acc[j] = (f32x4){0.f, 0.f, 0.f, 0.f};
        #pragma unroll
        for (int ks = 0; ks < 2; ++ks) {
            const int k0 = ks * 32 + lg * 8;
            const int arow = r0 + lr;
            bf16x8 a = *(const bf16x8*)(s_enc + ((arow * Hh + k0) ^ ((arow & 7) << 3)));
            #pragma unroll
            for (int j = 0; j < 6; ++j) {
                const int n = nb + j * 16 + lr;
                bf16x8 bf = *(const bf16x8*)(s_wT + ((n * Hh + k0) ^ ((n & 7) << 3)));
                acc[j] = __builtin_amdgcn_mfma_f32_16x16x32_bf16(a, bf, acc[j], 0, 0, 0);
            }
        }
        #pragma unroll
        for (int j = 0; j < 6; ++j) {
            const int nfull = nb + j * 16;
            const int cc = nfull + lr;
            if (nfull < 64) {               // gi (no bias)
                #pragma unroll
                for (int rr = 0; rr < 4; ++rr)
                    s_gi[r0 + lg * 4 + rr][cc] = acc[j][rr];
            } else if (nfull < 128) {       // gj + gate_b1
                const float bias = gate_b1[cc - 64];
                #pragma unroll
                for (int rr = 0; rr < 4; ++rr)
                    s_gj[r0 + lg * 4 + rr][cc - 64] = acc[j][rr] + bias;
            } else {                        // msgh = relu(. + msg_b1), bf16
                const float bias = msg_b1[cc - 128];
                #pragma unroll
                for (int rr = 0; rr < 4; ++rr) {
                    const int row = r0 + lg * 4 + rr;
                    float v = fmaxf(acc[j][rr] + bias, 0.f);
                    s_msgh[(row * Hh + (cc - 128)) ^ ((row & 7) << 3)] = f2b(v);
                }
            }
        }
    }
    __syncthreads();

    // ---------- phase 3: msg = msgh @ msg_w2 + msg_b2, M=64 K=64 N=64 ----------
    {
        const int c0 = (wv & 1) * 32;
        f32x4 acc[2];
        #pragma unroll
        for (int j = 0; j < 2; ++j) acc[j] = (f32x4){0.f, 0.f, 0.f, 0.f};
        #pragma unroll
        for (int ks = 0; ks < 2; ++ks) {
            const int k0 = ks * 32 + lg * 8;
            const int arow = r0 + lr;
            bf16x8 a = *(const bf16x8*)(s_msgh + ((arow * Hh + k0) ^ ((arow & 7) << 3)));
            #pragma unroll
            for (int j = 0; j < 2; ++j) {
                const int n = 192 + c0 + j * 16 + lr;
                bf16x8 bf = *(const bf16x8*)(s_wT + ((n * Hh + k0) ^ ((n & 7) << 3)));
                acc[j] = __builtin_amdgcn_mfma_f32_16x16x32_bf16(a, bf, acc[j], 0, 0, 0);
            }
        }
        #pragma unroll
        for (int j = 0; j < 2; ++j) {
            const int cc = c0 + j * 16 + lr;
            const float bias = msg_b2[cc];
            #pragma unroll
            for (int rr = 0; rr < 4; ++rr)
                s_msg[r0 + lg * 4 + rr][cc] = acc[j][rr] + bias;
        }
    }

    // ---------- gates[i][j] = sigmoid(relu(gi[i]+gj[j]).w2 + b2), lane=j ----------
    {
        const int row0g = wv * 8;
        float ag[8];
        #pragma unroll
        for (int r = 0; r < 8; ++r) ag[r] = 0.f;
        const float b2v = gate_b2[0];
        for (int h0 = 0; h0 < Hh; h0 += 4) {
            float4 gj4 = *(const float4*)&s_gj[lane][h0];
            float4 w24 = *(const float4*)&s_w2[h0];
            #pragma unroll
            for (int r = 0; r < 8; ++r) {
                float4 gi4 = *(const float4*)&s_gi[row0g + r][h0];
                ag[r] = fmaf(fmaxf(gi4.x + gj4.x, 0.f), w24.x, ag[r]);
                ag[r] = fmaf(fmaxf(gi4.y + gj4.y, 0.f), w24.y, ag[r]);
                ag[r] = fmaf(fmaxf(gi4.z + gj4.z, 0.f), w24.z, ag[r]);
                ag[r] = fmaf(fmaxf(gi4.w + gj4.w, 0.f), w24.w, ag[r]);
            }
        }
        #pragma unroll
        for (int r = 0; r < 8; ++r) {
            const float x = ag[r] + b2v;
            s_gates[row0g + r][lane] = 1.f / (1.f + __expf(-x));
        }
    }
    __syncthreads();

    // ---------- enhanced = gates @ msg, lane=h ----------
    {
        const int row0g = wv * 8;
        float ae[8];
        #pragma unroll
        for (int r = 0; r < 8; ++r) ae[r] = 0.f;
        for (int j0 = 0; j0 < Nn; j0 += 4) {
            const float m0 = s_msg[j0 + 0][lane];
            const float m1 = s_msg[j0 + 1][lane];
            const float m2 = s_msg[j0 + 2][lane];
            const float m3 = s_msg[j0 + 3][lane];
            #pragma unroll
            for (int r = 0; r < 8; ++r) {
                float4 g4 = *(const float4*)&s_gates[row0g + r][j0];
                ae[r] = fmaf(g4.x, m0, ae[r]);
                ae[r] = fmaf(g4.y, m1, ae[r]);
                ae[r] = fmaf(g4.z, m2, ae[r]);
                ae[r] = fmaf(g4.w, m3, ae[r]);
            }
        }
        #pragma unroll
        for (int r = 0; r < 8; ++r)
            out[((size_t)bb * Nn + row0g + r) * Hh + lane] = ae[r];
    }
}

extern "C" void kernel_launch(void* const* d_in, const int* in_sizes, int n_in,
                              void* d_out, int out_size, void* d_ws, size_t ws_size,
                              hipStream_t stream) {
    const float* obs     = (const float*)d_in[0];
    const float* enc_w   = (const float*)d_in[1];
    const float* enc_b   = (const float*)d_in[2];
    const float* gate_w1 = (const float*)d_in[3];
    const float* gate_b1 = (const float*)d_in[4];
    const float* gate_w2 = (const float*)d_in[5];
    const float* gate_b2 = (const float*)d_in[6];
    const float* msg_w1  = (const float*)d_in[7];
    const float* msg_b1  = (const float*)d_in[8];
    const float* msg_w2  = (const float*)d_in[9];
    const float* msg_b2  = (const float*)d_in[10];
    float* out = (float*)d_out;

    gcm_kernel<<<Bb, 512, 0, stream>>>(obs, enc_w, enc_b, gate_w1, gate_b1,
                                       gate_w2, gate_b2, msg_w1, msg_b1,
                                       msg_w2, msg_b2, out);
}

// Round 3
// 21.328 us; speedup vs baseline: 2.1216x; 1.3787x over previous
//
#include <hip/hip_runtime.h>

typedef float  f32x4  __attribute__((ext_vector_type(4)));
typedef short  bf16x8 __attribute__((ext_vector_type(8)));

#define Bb 256
#define Nn 64
#define Dd 128
#define Hh 64

// packed f32->bf16 (RNE), gfx950
__device__ __forceinline__ uint cvtpk(float lo, float hi) {
    uint r;
    asm("v_cvt_pk_bf16_f32 %0, %1, %2" : "=v"(r) : "v"(lo), "v"(hi));
    return r;
}

union U8 { uint u[4]; bf16x8 v; };

__global__ __launch_bounds__(1024) void gcm_kernel(
    const float* __restrict__ obs,      // B*N*D
    const float* __restrict__ enc_w,    // D*H
    const float* __restrict__ enc_b,    // H
    const float* __restrict__ gate_w1,  // 2H*H
    const float* __restrict__ gate_b1,  // H
    const float* __restrict__ gate_w2,  // H
    const float* __restrict__ gate_b2,  // 1
    const float* __restrict__ msg_w1,   // H*H
    const float* __restrict__ msg_b1,   // H
    const float* __restrict__ msg_w2,   // H*H
    const float* __restrict__ msg_b2,   // H
    float* __restrict__ out)            // B*N*H
{
    const int bb   = blockIdx.x;
    const int t    = threadIdx.x;
    const int lane = t & 63;
    const int wv   = t >> 6;            // 0..15
    const int lr   = lane & 15;
    const int lg   = lane >> 4;
    const int rt   = wv & 3;            // row-tile 0..3
    const int ct   = wv >> 2;           // col-tile 0..3

    // bf16 tiles: XOR swizzle on ELEMENT index: e ^= (row&7)<<3  (16B granule)
    __shared__ __align__(16) ushort s_encwT[Hh * Dd];  // 16KB [n<64][k<128]
    __shared__ __align__(16) ushort s_wT[256 * Hh];    // 32KB [n<256][k<64] wi|wj|mw1|mw2 (T)
    __shared__ __align__(16) ushort s_enc  [Nn * Hh];  // 8KB  [row][h]
    __shared__ __align__(16) ushort s_msgh [Nn * Hh];  // 8KB
    __shared__ __align__(16) ushort s_gatesb[Nn * Hh]; // 8KB  [i][j]
    __shared__ __align__(16) ushort s_msgT [Hh * Nn];  // 8KB  [h][j]
    // f32 tiles: XOR swizzle on float index: e ^= (row&7)<<2  (16B granule)
    __shared__ __align__(16) float  s_gi[Nn * Hh];     // 16KB
    __shared__ __align__(16) float  s_gj[Nn * Hh];     // 16KB
    __shared__ __align__(16) float  s_w2[Hh];

    // ---- 0a: prefetch obs A-slice (this wave's row-tile) ----
    float4 pf[8];
    {
        const float* ob = obs + ((size_t)bb * Nn + rt * 16 + lr) * Dd + lg * 8;
        #pragma unroll
        for (int ks = 0; ks < 4; ++ks) {
            pf[2 * ks]     = *(const float4*)(ob + ks * 32);
            pf[2 * ks + 1] = *(const float4*)(ob + ks * 32 + 4);
        }
    }

    if (t < Hh) s_w2[t] = gate_w2[t];

    // ---- 0b: stage enc_w^T bf16 swizzled (float4 over n, scatter-transpose) ----
    #pragma unroll
    for (int it = 0; it < 2; ++it) {
        const int g  = t + it * 1024;        // 0..2047
        const int k  = g >> 4;               // 0..127
        const int n0 = (g & 15) * 4;
        float4 w4 = *(const float4*)(enc_w + k * Hh + n0);
        uint pA = cvtpk(w4.x, w4.y), pB = cvtpk(w4.z, w4.w);
        s_encwT[((n0 + 0) * Dd + k) ^ (((n0 + 0) & 7) << 3)] = (ushort)pA;
        s_encwT[((n0 + 1) * Dd + k) ^ (((n0 + 1) & 7) << 3)] = (ushort)(pA >> 16);
        s_encwT[((n0 + 2) * Dd + k) ^ (((n0 + 2) & 7) << 3)] = (ushort)pB;
        s_encwT[((n0 + 3) * Dd + k) ^ (((n0 + 3) & 7) << 3)] = (ushort)(pB >> 16);
    }

    // ---- 0c: convert obs -> bf16 A-fragments ----
    bf16x8 afrag[4];
    #pragma unroll
    for (int ks = 0; ks < 4; ++ks) {
        U8 u;
        u.u[0] = cvtpk(pf[2 * ks].x,     pf[2 * ks].y);
        u.u[1] = cvtpk(pf[2 * ks].z,     pf[2 * ks].w);
        u.u[2] = cvtpk(pf[2 * ks + 1].x, pf[2 * ks + 1].y);
        u.u[3] = cvtpk(pf[2 * ks + 1].z, pf[2 * ks + 1].w);
        afrag[ks] = u.v;
    }

    // ---- 0d: issue wT weight loads (land during phase 1) ----
    float4 pfw[4];
    {
        const int k  = t >> 4;               // 0..63
        const int n0 = (t & 15) * 4;
        const float* s0 = gate_w1 + k * Hh + n0;            // w_i
        const float* s1 = gate_w1 + (Hh + k) * Hh + n0;     // w_j
        const float* s2 = msg_w1 + k * Hh + n0;
        const float* s3 = msg_w2 + k * Hh + n0;
        pfw[0] = *(const float4*)s0;
        pfw[1] = *(const float4*)s1;
        pfw[2] = *(const float4*)s2;
        pfw[3] = *(const float4*)s3;
    }

    __syncthreads();   // B1: s_encwT ready

    // ---------- phase 1: enc = relu(obs @ enc_w + b), wave tile (rt, ct) ----------
    {
        f32x4 acc = (f32x4){0.f, 0.f, 0.f, 0.f};
        const int n = ct * 16 + lr;
        #pragma unroll
        for (int ks = 0; ks < 4; ++ks) {
            const int k0 = ks * 32 + lg * 8;
            bf16x8 bf = *(const bf16x8*)(s_encwT + ((n * Dd + k0) ^ ((n & 7) << 3)));
            acc = __builtin_amdgcn_mfma_f32_16x16x32_bf16(afrag[ks], bf, acc, 0, 0, 0);
        }
        // stage wT (transposed scatter) while MFMA drains
        #pragma unroll
        for (int it = 0; it < 4; ++it) {
            const int k  = t >> 4;
            const int n0 = it * 64 + (t & 15) * 4;
            uint pA = cvtpk(pfw[it].x, pfw[it].y), pB = cvtpk(pfw[it].z, pfw[it].w);
            s_wT[((n0 + 0) * Hh + k) ^ (((n0 + 0) & 7) << 3)] = (ushort)pA;
            s_wT[((n0 + 1) * Hh + k) ^ (((n0 + 1) & 7) << 3)] = (ushort)(pA >> 16);
            s_wT[((n0 + 2) * Hh + k) ^ (((n0 + 2) & 7) << 3)] = (ushort)pB;
            s_wT[((n0 + 3) * Hh + k) ^ (((n0 + 3) & 7) << 3)] = (ushort)(pB >> 16);
        }
        // epilogue: bias+relu -> s_enc bf16
        const float be = enc_b[n];
        float v0 = fmaxf(acc[0] + be, 0.f), v1 = fmaxf(acc[1] + be, 0.f);
        float v2 = fmaxf(acc[2] + be, 0.f), v3 = fmaxf(acc[3] + be, 0.f);
        uint pA = cvtpk(v0, v1), pB = cvtpk(v2, v3);
        const int rb = rt * 16 + lg * 4;
        s_enc[((rb + 0) * Hh + n) ^ (((rb + 0) & 7) << 3)] = (ushort)pA;
        s_enc[((rb + 1) * Hh + n) ^ (((rb + 1) & 7) << 3)] = (ushort)(pA >> 16);
        s_enc[((rb + 2) * Hh + n) ^ (((rb + 2) & 7) << 3)] = (ushort)pB;
        s_enc[((rb + 3) * Hh + n) ^ (((rb + 3) & 7) << 3)] = (ushort)(pB >> 16);
    }
    __syncthreads();   // B2: s_enc + s_wT ready

    // ---------- phase 2: [gi|gj|msgh] = enc @ [wi|wj|mw1]; wave: rt, cols (ct*3+q) ----------
    {
        f32x4 acc[3];
        #pragma unroll
        for (int q = 0; q < 3; ++q) acc[q] = (f32x4){0.f, 0.f, 0.f, 0.f};
        const int arow = rt * 16 + lr;
        #pragma unroll
        for (int ks = 0; ks < 2; ++ks) {
            const int k0 = ks * 32 + lg * 8;
            bf16x8 a = *(const bf16x8*)(s_enc + ((arow * Hh + k0) ^ ((arow & 7) << 3)));
            #pragma unroll
            for (int q = 0; q < 3; ++q) {
                const int n = (ct * 3 + q) * 16 + lr;
                bf16x8 bf = *(const bf16x8*)(s_wT + ((n * Hh + k0) ^ ((n & 7) << 3)));
                acc[q] = __builtin_amdgcn_mfma_f32_16x16x32_bf16(a, bf, acc[q], 0, 0, 0);
            }
        }
        const int rb = rt * 16 + lg * 4;
        #pragma unroll
        for (int q = 0; q < 3; ++q) {
            const int nfull = (ct * 3 + q) * 16;
            const int cc = nfull + lr;
            if (nfull < 64) {                      // gi, no bias, f32 swizzled
                #pragma unroll
                for (int rr = 0; rr < 4; ++rr) {
                    const int row = rb + rr;
                    s_gi[(row * Hh + cc) ^ ((row & 7) << 2)] = acc[q][rr];
                }
            } else if (nfull < 128) {              // gj + gate_b1
                const float b1 = gate_b1[cc - 64];
                #pragma unroll
                for (int rr = 0; rr < 4; ++rr) {
                    const int row = rb + rr;
                    s_gj[(row * Hh + (cc - 64)) ^ ((row & 7) << 2)] = acc[q][rr] + b1;
                }
            } else {                               // msgh = relu(.+msg_b1) bf16
                const float bm = msg_b1[cc - 128];
                float v0 = fmaxf(acc[q][0] + bm, 0.f), v1 = fmaxf(acc[q][1] + bm, 0.f);
                float v2 = fmaxf(acc[q][2] + bm, 0.f), v3 = fmaxf(acc[q][3] + bm, 0.f);
                uint pA = cvtpk(v0, v1), pB = cvtpk(v2, v3);
                const int c2 = cc - 128;
                s_msgh[((rb + 0) * Hh + c2) ^ (((rb + 0) & 7) << 3)] = (ushort)pA;
                s_msgh[((rb + 1) * Hh + c2) ^ (((rb + 1) & 7) << 3)] = (ushort)(pA >> 16);
                s_msgh[((rb + 2) * Hh + c2) ^ (((rb + 2) & 7) << 3)] = (ushort)pB;
                s_msgh[((rb + 3) * Hh + c2) ^ (((rb + 3) & 7) << 3)] = (ushort)(pB >> 16);
            }
        }
    }
    __syncthreads();   // B3: gi/gj/msgh ready

    // ---------- phase 3: msg = msgh @ msg_w2 + b2 -> s_msgT bf16 [h][j] ----------
    {
        f32x4 acc = (f32x4){0.f, 0.f, 0.f, 0.f};
        const int arow = rt * 16 + lr;
        const int n = 192 + ct * 16 + lr;
        #pragma unroll
        for (int ks = 0; ks < 2; ++ks) {
            const int k0 = ks * 32 + lg * 8;
            bf16x8 a = *(const bf16x8*)(s_msgh + ((arow * Hh + k0) ^ ((arow & 7) << 3)));
            bf16x8 bf = *(const bf16x8*)(s_wT + ((n * Hh + k0) ^ ((n & 7) << 3)));
            acc = __builtin_amdgcn_mfma_f32_16x16x32_bf16(a, bf, acc, 0, 0, 0);
        }
        const int h  = ct * 16 + lr;           // msg col
        const int jb = rt * 16 + lg * 4;       // 4 consecutive msg rows
        const float bm2 = msg_b2[h];
        uint pA = cvtpk(acc[0] + bm2, acc[1] + bm2);
        uint pB = cvtpk(acc[2] + bm2, acc[3] + bm2);
        const int e = (h * Nn + jb) ^ ((h & 7) << 3);
        *(uint*)(s_msgT + e)     = pA;         // 8B-aligned: jb%4==0, swz flips bits>=3
        *(uint*)(s_msgT + e + 2) = pB;
    }

    // ---------- gates: sigmoid(relu(gi[i]+gj[j]).w2 + b2), lane=j, 4 rows/wave ----------
    {
        const int row0g = wv * 4;
        float ag[4] = {0.f, 0.f, 0.f, 0.f};
        #pragma unroll 4
        for (int h0 = 0; h0 < Hh; h0 += 4) {
            float4 gj4 = *(const float4*)&s_gj[(lane * Hh + h0) ^ ((lane & 7) << 2)];
            float4 w24 = *(const float4*)&s_w2[h0];
            #pragma unroll
            for (int r = 0; r < 4; ++r) {
                const int row = row0g + r;
                float4 gi4 = *(const float4*)&s_gi[(row * Hh + h0) ^ ((row & 7) << 2)];
                ag[r] = fmaf(fmaxf(gi4.x + gj4.x, 0.f), w24.x, ag[r]);
                ag[r] = fmaf(fmaxf(gi4.y + gj4.y, 0.f), w24.y, ag[r]);
                ag[r] = fmaf(fmaxf(gi4.z + gj4.z, 0.f), w24.z, ag[r]);
                ag[r] = fmaf(fmaxf(gi4.w + gj4.w, 0.f), w24.w, ag[r]);
            }
        }
        const float b2v = gate_b2[0];
        float g0 = 1.f / (1.f + __expf(-(ag[0] + b2v)));
        float g1 = 1.f / (1.f + __expf(-(ag[1] + b2v)));
        float g2 = 1.f / (1.f + __expf(-(ag[2] + b2v)));
        float g3 = 1.f / (1.f + __expf(-(ag[3] + b2v)));
        uint pA = cvtpk(g0, g1), pB = cvtpk(g2, g3);
        s_gatesb[((row0g + 0) * Hh + lane) ^ (((row0g + 0) & 7) << 3)] = (ushort)pA;
        s_gatesb[((row0g + 1) * Hh + lane) ^ (((row0g + 1) & 7) << 3)] = (ushort)(pA >> 16);
        s_gatesb[((row0g + 2) * Hh + lane) ^ (((row0g + 2) & 7) << 3)] = (ushort)pB;
        s_gatesb[((row0g + 3) * Hh + lane) ^ (((row0g + 3) & 7) << 3)] = (ushort)(pB >> 16);
    }
    __syncthreads();   // B4: gates + msgT ready

    // ---------- enhanced = gates @ msg (MFMA), wave tile (rt, ct) ----------
    {
        f32x4 acc = (f32x4){0.f, 0.f, 0.f, 0.f};
        const int arow = rt * 16 + lr;
        const int n = ct * 16 + lr;            // h
        #pragma unroll
        for (int ks = 0; ks < 2; ++ks) {
            const int k0 = ks * 32 + lg * 8;
            bf16x8 a = *(const bf16x8*)(s_gatesb + ((arow * Hh + k0) ^ ((arow & 7) << 3)));
            bf16x8 bf = *(const bf16x8*)(s_msgT + ((n * Nn + k0) ^ ((n & 7) << 3)));
            acc = __builtin_amdgcn_mfma_f32_16x16x32_bf16(a, bf, acc, 0, 0, 0);
        }
        const int rb = rt * 16 + lg * 4;
        #pragma unroll
        for (int rr = 0; rr < 4; ++rr)
            out[((size_t)bb * Nn + rb + rr) * Hh + n] = acc[rr];
    }
}

extern "C" void kernel_launch(void* const* d_in, const int* in_sizes, int n_in,
                              void* d_out, int out_size, void* d_ws, size_t ws_size,
                              hipStream_t stream) {
    const float* obs     = (const float*)d_in[0];
    const float* enc_w   = (const float*)d_in[1];
    const float* enc_b   = (const float*)d_in[2];
    const float* gate_w1 = (const float*)d_in[3];
    const float* gate_b1 = (const float*)d_in[4];
    const float* gate_w2 = (const float*)d_in[5];
    const float* gate_b2 = (const float*)d_in[6];
    const float* msg_w1  = (const float*)d_in[7];
    const float* msg_b1  = (const float*)d_in[8];
    const float* msg_w2  = (const float*)d_in[9];
    const float* msg_b2  = (const float*)d_in[10];
    float* out = (float*)d_out;

    gcm_kernel<<<Bb, 1024, 0, stream>>>(obs, enc_w, enc_b, gate_w1, gate_b1,
                                        gate_w2, gate_b2, msg_w1, msg_b1,
                                        msg_w2, msg_b2, out);
}